// Round 2
// baseline (103.782 us; speedup 1.0000x reference)
//
#include <hip/hip_runtime.h>
#include <stdint.h>

// Fused dynamic-filter network op, bf16 MFMA implicit-GEMM, pipelined.
//   filt[n,oc,h,w] = bc[oc] + sum_{ic,kh,kw} gt_zpad[n,ic,h+kh-1,w+kw-1]*Wc[oc,ic,kh,kw]
//   out[n,c,h,w]   = sum_{k=kh*3+kw} filt[n,c*9+k,h,w] * gr_reppad[n,c,h+kh-1,w+kw-1]
// N=8, C=64, H=W=128, OC=576. filt (302 MB) never materialized.
//
// ws layout:
//   [0, 663552)          Wc bf16, 36 blocks of [144 oc][64 ic], XOR-swizzled,
//                        oc rows PERMUTED: tile row r holds oc (r&15)*9 + (r>>4)
//   [663552, 680192)     16640 B of zeros (OOB row source for conv zero-pad in h)
//   [680192, 17719552)   gt bf16 row-blocks [n][y]: [130 r=w+1][64 ic], swizzled,
//                        r=0 and r=129 are zero rows (conv zero-pad in w)
//
// R11 vs R10: B (Wc) fragments read DIRECTLY from global (L1/L2-hot: same 18KB
// tile shared by 8 waves x 256 blocks) into a 6-deep register ring, issued 6
// MFMA-groups (~460 cy) ahead. LDS holds ONLY A (6 row slots, all staged in the
// prologue -> no slot reuse). Consequences:
//  - LDS reads per tap per wave: 26 -> 8 (A only); LDS writes: A staging only.
//  - Barriers: 5 -> 1 (prologue). Waves drift freely -> LDS/VMEM bursts of one
//    wave overlap the other wave's MFMA bursts (we are locked at 2 waves/SIMD
//    by acc=144 regs, so overlap must come from ILP + drift, not occupancy).
//  - A fragments software-pipelined: next tap's kk0 ds_reads issue after group
//    8, kk1 after group 17 (10-group distance).

typedef short bf16x8 __attribute__((ext_vector_type(8)));
typedef float f32x4 __attribute__((ext_vector_type(4)));

#define ROWBLK_B 16640
#define BTAP_B   18432
#define ZERO_OFF 663552
#define GTB_OFF  (ZERO_OFF + ROWBLK_B)

__device__ __forceinline__ uint32_t f2bf(float f) {
  uint32_t x = __float_as_uint(f);
  return (x + 0x7FFFu + ((x >> 16) & 1u)) >> 16;   // RNE
}

__device__ __forceinline__ void gload_lds16(const void* g, void* l) {
  __builtin_amdgcn_global_load_lds(
      (const __attribute__((address_space(1))) void*)g,
      (__attribute__((address_space(3))) void*)l, 16, 0, 0);
}

// ---- prep 1: Wc [576][64][3][3] f32 -> ws bf16 [tap*4+octile][144][64], pre-swizzled.
// Tile row r holds original oc = octile*144 + (r&15)*9 + (r>>4)  (pi permutation:
// D-row nf*16 + l4*4+q  ->  channel l4*4+q, dyn-tap nf).
__global__ void prep_wc(const float* __restrict__ Wc, uint8_t* __restrict__ ws) {
  int ch = blockIdx.x * 256 + threadIdx.x;   // 41472 x 16B chunks, exact
  int tb = ch / 1152;                        // tap*4 + octile
  int cw = ch - tb * 1152;
  int tap = tb >> 2, octile = tb & 3;
  int row = cw >> 3, sl = cw & 7;
  int slot = sl ^ (row & 7);                 // pre-apply read-side XOR swizzle
  int ic0 = slot * 8;
  int oc = octile * 144 + (row & 15) * 9 + (row >> 4);   // pi permutation
  uint32_t p[4];
#pragma unroll
  for (int e = 0; e < 4; ++e) {
    uint32_t lo = f2bf(Wc[(oc * 64 + ic0 + 2 * e) * 9 + tap]);
    uint32_t hi = f2bf(Wc[(oc * 64 + ic0 + 2 * e + 1) * 9 + tap]);
    p[e] = lo | (hi << 16);
  }
  uint4 u; u.x = p[0]; u.y = p[1]; u.z = p[2]; u.w = p[3];
  *(uint4*)(ws + (size_t)tb * BTAP_B + (size_t)cw * 16) = u;
}

// ---- prep 2: gt [8][64][128][128] f32 -> ws bf16 row-blocks, pre-swizzled, padded
__global__ void prep_gt(const float* __restrict__ gt, uint8_t* __restrict__ ws) {
  int b = blockIdx.x;
  if (b == 1024) {  // zero block for out-of-image rows
    uint4 z; z.x = z.y = z.z = z.w = 0;
    for (int i = threadIdx.x; i < 1040; i += 256)
      *(uint4*)(ws + ZERO_OFF + (size_t)i * 16) = z;
    return;
  }
  int n = b >> 7, y = b & 127;
  uint8_t* base = ws + GTB_OFF + (size_t)b * ROWBLK_B;
  for (int i = threadIdx.x; i < 1040; i += 256) {   // 1040 x 16B chunks per row-block
    int r = i >> 3, sl = i & 7;
    int slot = sl ^ (r & 7);
    uint4 u; u.x = u.y = u.z = u.w = 0;
    if (r >= 1 && r <= 128) {
      int w = r - 1, ic0 = slot * 8;
      uint32_t p[4];
#pragma unroll
      for (int e = 0; e < 4; ++e) {
        uint32_t lo = f2bf(gt[((n * 64 + ic0 + 2 * e) * 128 + y) * 128 + w]);
        uint32_t hi = f2bf(gt[((n * 64 + ic0 + 2 * e + 1) * 128 + y) * 128 + w]);
        p[e] = lo | (hi << 16);
      }
      u.x = p[0]; u.y = p[1]; u.z = p[2]; u.w = p[3];
    }
    *(uint4*)(base + (size_t)i * 16) = u;
  }
}

// ---- main: per block M=512 pixels (4 rows x 128 w) x N=144 oc, K=576
__global__ __launch_bounds__(512, 2) void dfn_mfma(
    const float* __restrict__ gr, const float* __restrict__ bc,
    const uint8_t* __restrict__ ws, float* __restrict__ out) {
  __shared__ uint8_t smem[99840];            // A only: 6 slots x 16640
  uint8_t* Abuf = smem;
  const int tid = threadIdx.x;
  const int lane = tid & 63;
  const int wv = tid >> 6;
  const int l15 = lane & 15;
  const int l4 = lane >> 4;
  // XCD-coscheduling decode: bits[2:0]=nh_low, bits[4:3]=octile, bits[9:5]=nh_high.
  const int bid = blockIdx.x;
  const int octile = (bid >> 3) & 3;
  const int nh = (bid & 7) | ((bid >> 5) << 3);
  const int n = nh >> 5;
  const int h0 = (nh & 31) * 4;

  // ---- precomputed per-lane offsets (swizzle algebra, zero inner VALU)
  int bo[2], aoff[3][2];
#pragma unroll
  for (int kk = 0; kk < 2; ++kk) {
    bo[kk] = l15 * 128 + ((kk * 64 + l4 * 16) ^ ((l15 & 7) << 4));
#pragma unroll
    for (int dwp = 0; dwp < 3; ++dwp) {
      int rl = l15 + dwp;
      aoff[dwp][kk] = rl * 128 + ((kk * 64 + l4 * 16) ^ ((rl & 7) << 4));
    }
  }
  int ab[4];                                  // per-mf A base: slot-row + w-col
#pragma unroll
  for (int mf = 0; mf < 4; ++mf) {
    int m = wv * 4 + mf;
    ab[mf] = (m >> 3) * ROWBLK_B + (m & 7) * 2048;
  }

  const uint8_t* gtb = ws + GTB_OFF;
  const uint8_t* zblk = ws + ZERO_OFF;

#define ISSUE_AROW(Y, SLOT) do {                                              \
    int y_ = (Y);                                                             \
    const uint8_t* src_ = (y_ >= 0 && y_ < 128)                               \
        ? (gtb + (size_t)(n * 128 + y_) * ROWBLK_B) : zblk;                   \
    uint8_t* dst_ = Abuf + (SLOT) * ROWBLK_B;                                 \
    _Pragma("unroll")                                                         \
    for (int it = 0; it < 3; ++it) {                                          \
      int idx = it * 512 + tid;                                               \
      if (idx < 1040)                                                         \
        gload_lds16(src_ + (size_t)idx * 16,                                  \
                    dst_ + (size_t)(it * 512 + (tid & ~63)) * 16);            \
    }                                                                         \
  } while (0)

  f32x4 acc[4][9];
  bf16x8 bq[6];                               // global->reg B ring, 6 deep
  bf16x8 afr0[4], afr1[4];                    // A frags for kk=0 / kk=1

// One tap = 18 MFMA groups (kk0 nf0..8, kk1 nf0..8). Group g consumes ring
// slot g%6 and issues B frag g+6 (wrapping into tap T+1). Next tap's A
// ds_reads issue after the last consumer of each afr set (g==8 / g==17).
#define TAPX(T, DH, DWP, NDH, NDWP, HASNEXT) do {                             \
    _Pragma("unroll")                                                         \
    for (int g = 0; g < 18; ++g) {                                            \
      const int nf = g % 9;                                                   \
      bf16x8 bcur_ = bq[g % 6];                                               \
      __builtin_amdgcn_s_setprio(1);                                          \
      _Pragma("unroll")                                                       \
      for (int mf = 0; mf < 4; ++mf)                                          \
        acc[mf][nf] = __builtin_amdgcn_mfma_f32_16x16x32_bf16(                \
            bcur_, (g < 9 ? afr0[mf] : afr1[mf]), acc[mf][nf], 0, 0, 0);      \
      __builtin_amdgcn_s_setprio(0);                                          \
      if ((HASNEXT) || g < 12) {                                              \
        const int f2 = g + 6;                                                 \
        const int t2 = f2 < 18 ? (T) : (T) + 1;                               \
        const int ff = f2 < 18 ? f2 : f2 - 18;                                \
        bq[g % 6] = *(const bf16x8*)(ws + (size_t)(t2 * 4 + octile) * BTAP_B  \
                                     + bo[ff / 9] + (ff % 9) * 2048);         \
      }                                                                       \
      if ((HASNEXT) && g == 8) {                                              \
        _Pragma("unroll")                                                     \
        for (int mf = 0; mf < 4; ++mf)                                        \
          afr0[mf] = *(const bf16x8*)(Abuf + ab[mf]                           \
                                      + ((NDH) + 1) * ROWBLK_B               \
                                      + aoff[NDWP][0]);                       \
      }                                                                       \
      if ((HASNEXT) && g == 17) {                                             \
        _Pragma("unroll")                                                     \
        for (int mf = 0; mf < 4; ++mf)                                        \
          afr1[mf] = *(const bf16x8*)(Abuf + ab[mf]                           \
                                      + ((NDH) + 1) * ROWBLK_B               \
                                      + aoff[NDWP][1]);                       \
      }                                                                       \
    }                                                                         \
  } while (0)

  // ---- prologue: stage ALL 6 A rows (h0-1 .. h0+4); prefetch tap-0 B frags
#pragma unroll
  for (int row = 0; row < 6; ++row) ISSUE_AROW(h0 - 1 + row, row);
#pragma unroll
  for (int f = 0; f < 6; ++f)
    bq[f] = *(const bf16x8*)(ws + (size_t)octile * BTAP_B
                             + bo[f / 9] + (f % 9) * 2048);

  // bias init overlaps the staging loads: acc[mf][nf][q] = bc for
  // oc = octile*144 + (l4*4+q)*9 + nf  (channel l4*4+q, dyn-tap nf)
#pragma unroll
  for (int nf = 0; nf < 9; ++nf) {
#pragma unroll
    for (int q = 0; q < 4; ++q) {
      float bias = bc[octile * 144 + (l4 * 4 + q) * 9 + nf];
      acc[0][nf][q] = bias; acc[1][nf][q] = bias;
      acc[2][nf][q] = bias; acc[3][nf][q] = bias;
    }
  }
  __syncthreads();                            // the ONLY barrier

  // tap 0 A fragments (DH=-1 -> slot offset 0, DWP=0)
#pragma unroll
  for (int mf = 0; mf < 4; ++mf)
    afr0[mf] = *(const bf16x8*)(Abuf + ab[mf] + aoff[0][0]);
#pragma unroll
  for (int mf = 0; mf < 4; ++mf)
    afr1[mf] = *(const bf16x8*)(Abuf + ab[mf] + aoff[0][1]);

  // ---- 9 taps, barrier-free
  TAPX(0, -1, 0, -1, 1, 1);
  TAPX(1, -1, 1, -1, 2, 1);
  TAPX(2, -1, 2,  0, 0, 1);
  TAPX(3,  0, 0,  0, 1, 1);
  TAPX(4,  0, 1,  0, 2, 1);
  TAPX(5,  0, 2,  1, 0, 1);
  TAPX(6,  1, 0,  1, 1, 1);
  TAPX(7,  1, 1,  1, 2, 1);
  TAPX(8,  1, 2,  0, 0, 0);

  // ---- epilogue: register-direct. acc[mf][k][q] = filt(pixel(mf,l15),
  // channel l4*4+q, tap k). Pure VALU + global; no LDS.
  const float* grb = gr + (size_t)(n * 64 + octile * 16 + l4 * 4) * 16384;
  float* outb = out + (size_t)(n * 64 + octile * 16 + l4 * 4) * 16384;
#pragma unroll
  for (int mf = 0; mf < 4; ++mf) {
    int p = (wv * 4 + mf) * 16 + l15;         // pixel within 512-pixel tile
    int hrow = p >> 7, w = p & 127;
    int h = h0 + hrow;
    int off[3][3];                            // replicate-clamped, shared over q
#pragma unroll
    for (int i = 0; i < 3; ++i) {
      int yy = h + i - 1; yy = yy < 0 ? 0 : (yy > 127 ? 127 : yy);
#pragma unroll
      for (int j = 0; j < 3; ++j) {
        int xx = w + j - 1; xx = xx < 0 ? 0 : (xx > 127 ? 127 : xx);
        off[i][j] = yy * 128 + xx;
      }
    }
#pragma unroll
    for (int q = 0; q < 4; ++q) {
      const float* grc = grb + (size_t)q * 16384;
      float s = 0.f;
#pragma unroll
      for (int i = 0; i < 3; ++i)
#pragma unroll
        for (int j = 0; j < 3; ++j)
          s = fmaf(acc[mf][i * 3 + j][q], grc[off[i][j]], s);
      outb[(size_t)q * 16384 + h * 128 + w] = s;
    }
  }
}

extern "C" void kernel_launch(void* const* d_in, const int* in_sizes, int n_in,
                              void* d_out, int out_size, void* d_ws, size_t ws_size,
                              hipStream_t stream) {
  const float* gr = (const float*)d_in[0];
  const float* gt = (const float*)d_in[1];
  const float* Wc = (const float*)d_in[2];
  const float* bc = (const float*)d_in[3];
  uint8_t* ws = (uint8_t*)d_ws;
  float* out = (float*)d_out;

  prep_wc<<<162, 256, 0, stream>>>(Wc, ws);
  prep_gt<<<1025, 256, 0, stream>>>(gt, ws);
  dfn_mfma<<<1024, 512, 0, stream>>>(gr, bc, ws, out);
}

// Round 3
// 96.204 us; speedup vs baseline: 1.0788x; 1.0788x over previous
//
#include <hip/hip_runtime.h>
#include <stdint.h>

// Fused dynamic-filter network op, bf16 MFMA implicit-GEMM, pipelined.
//   filt[n,oc,h,w] = bc[oc] + sum_{ic,kh,kw} gt_zpad[n,ic,h+kh-1,w+kw-1]*Wc[oc,ic,kh,kw]
//   out[n,c,h,w]   = sum_{k=kh*3+kw} filt[n,c*9+k,h,w] * gr_reppad[n,c,h+kh-1,w+kw-1]
// N=8, C=64, H=W=128, OC=576. filt (302 MB) never materialized.
//
// ws layout:
//   [0, 663552)          Wc bf16, 36 blocks of [144 oc][64 ic], XOR-swizzled,
//                        oc rows PERMUTED: tile row r holds oc (r&15)*9 + (r>>4)
//   [663552, 680192)     16640 B of zeros (OOB row source for conv zero-pad in h)
//   [680192, 17719552)   gt bf16 row-blocks [n][y]: [130 r=w+1][64 ic], swizzled,
//                        r=0 and r=129 are zero rows (conv zero-pad in w)
//
// R12 vs R10 (R11's global-direct B reverted: L1-BW-bound, regressed):
// fragment reads software-pipelined ACROSS kk-half boundaries so the LDS pipe
// and MFMA pipe run concurrently instead of alternating (R10 wall ~= LDS + MFMA
// summed; both floors ~42 us):
//  - B ring br[4], read-ahead 3 MFMA-groups, frag index continuous over the
//    whole 2-tap window (36 frags) -> no read bunching at kk/tap boundaries.
//  - A double-buffer ar[2][4]: next half's 4 ds_reads issued one per group at
//    g=5..8 of the current half.
//  - Only the 5 post-barrier window storms bunch (4 A + 3 B reads).
// Same B-in-LDS buffers, same window/barrier schedule as R10, same register
// epilogue as R10/R11. Accumulation order bit-identical.

typedef short bf16x8 __attribute__((ext_vector_type(8)));
typedef float f32x4 __attribute__((ext_vector_type(4)));

#define ROWBLK_B 16640
#define BTAP_B   18432
#define ZERO_OFF 663552
#define GTB_OFF  (ZERO_OFF + ROWBLK_B)

__device__ __forceinline__ uint32_t f2bf(float f) {
  uint32_t x = __float_as_uint(f);
  return (x + 0x7FFFu + ((x >> 16) & 1u)) >> 16;   // RNE
}

__device__ __forceinline__ void gload_lds16(const void* g, void* l) {
  __builtin_amdgcn_global_load_lds(
      (const __attribute__((address_space(1))) void*)g,
      (__attribute__((address_space(3))) void*)l, 16, 0, 0);
}

// ---- prep 1: Wc [576][64][3][3] f32 -> ws bf16 [tap*4+octile][144][64], pre-swizzled.
// Tile row r holds original oc = octile*144 + (r&15)*9 + (r>>4)  (pi permutation:
// D-row nf*16 + l4*4+q  ->  channel l4*4+q, dyn-tap nf).
__global__ void prep_wc(const float* __restrict__ Wc, uint8_t* __restrict__ ws) {
  int ch = blockIdx.x * 256 + threadIdx.x;   // 41472 x 16B chunks, exact
  int tb = ch / 1152;                        // tap*4 + octile
  int cw = ch - tb * 1152;
  int tap = tb >> 2, octile = tb & 3;
  int row = cw >> 3, sl = cw & 7;
  int slot = sl ^ (row & 7);                 // pre-apply read-side XOR swizzle
  int ic0 = slot * 8;
  int oc = octile * 144 + (row & 15) * 9 + (row >> 4);   // pi permutation
  uint32_t p[4];
#pragma unroll
  for (int e = 0; e < 4; ++e) {
    uint32_t lo = f2bf(Wc[(oc * 64 + ic0 + 2 * e) * 9 + tap]);
    uint32_t hi = f2bf(Wc[(oc * 64 + ic0 + 2 * e + 1) * 9 + tap]);
    p[e] = lo | (hi << 16);
  }
  uint4 u; u.x = p[0]; u.y = p[1]; u.z = p[2]; u.w = p[3];
  *(uint4*)(ws + (size_t)tb * BTAP_B + (size_t)cw * 16) = u;
}

// ---- prep 2: gt [8][64][128][128] f32 -> ws bf16 row-blocks, pre-swizzled, padded
__global__ void prep_gt(const float* __restrict__ gt, uint8_t* __restrict__ ws) {
  int b = blockIdx.x;
  if (b == 1024) {  // zero block for out-of-image rows
    uint4 z; z.x = z.y = z.z = z.w = 0;
    for (int i = threadIdx.x; i < 1040; i += 256)
      *(uint4*)(ws + ZERO_OFF + (size_t)i * 16) = z;
    return;
  }
  int n = b >> 7, y = b & 127;
  uint8_t* base = ws + GTB_OFF + (size_t)b * ROWBLK_B;
  for (int i = threadIdx.x; i < 1040; i += 256) {   // 1040 x 16B chunks per row-block
    int r = i >> 3, sl = i & 7;
    int slot = sl ^ (r & 7);
    uint4 u; u.x = u.y = u.z = u.w = 0;
    if (r >= 1 && r <= 128) {
      int w = r - 1, ic0 = slot * 8;
      uint32_t p[4];
#pragma unroll
      for (int e = 0; e < 4; ++e) {
        uint32_t lo = f2bf(gt[((n * 64 + ic0 + 2 * e) * 128 + y) * 128 + w]);
        uint32_t hi = f2bf(gt[((n * 64 + ic0 + 2 * e + 1) * 128 + y) * 128 + w]);
        p[e] = lo | (hi << 16);
      }
      u.x = p[0]; u.y = p[1]; u.z = p[2]; u.w = p[3];
    }
    *(uint4*)(base + (size_t)i * 16) = u;
  }
}

// ---- main: per block M=512 pixels (4 rows x 128 w) x N=144 oc, K=576
__global__ __launch_bounds__(512, 2) void dfn_mfma(
    const float* __restrict__ gr, const float* __restrict__ bc,
    const uint8_t* __restrict__ ws, float* __restrict__ out) {
  __shared__ uint8_t smem[156928];           // A 5x16640=83200 + B 4x18432=73728
  uint8_t* Abuf = smem;
  uint8_t* Bbuf = smem + 83200;
  const int tid = threadIdx.x;
  const int lane = tid & 63;
  const int wv = tid >> 6;
  const int l15 = lane & 15;
  const int l4 = lane >> 4;
  // XCD-coscheduling decode: bits[2:0]=nh_low, bits[4:3]=octile, bits[9:5]=nh_high.
  const int bid = blockIdx.x;
  const int octile = (bid >> 3) & 3;
  const int nh = (bid & 7) | ((bid >> 5) << 3);
  const int n = nh >> 5;
  const int h0 = (nh & 31) * 4;

  // ---- precomputed per-lane ds_read offsets (swizzle algebra, zero inner VALU)
  int bo[2], aoff[3][2];
#pragma unroll
  for (int kk = 0; kk < 2; ++kk) {
    bo[kk] = l15 * 128 + ((kk * 64 + l4 * 16) ^ ((l15 & 7) << 4));
#pragma unroll
    for (int dwp = 0; dwp < 3; ++dwp) {
      int rl = l15 + dwp;
      aoff[dwp][kk] = rl * 128 + ((kk * 64 + l4 * 16) ^ ((rl & 7) << 4));
    }
  }
  int mrow[4], mcol[4];                      // wave-uniform (SGPR-able)
#pragma unroll
  for (int mf = 0; mf < 4; ++mf) {
    mrow[mf] = (wv * 4 + mf) >> 3;           // image-row index within block tile
    mcol[mf] = ((wv * 4 + mf) & 7) * 2048;   // wbase*128
  }

  const uint8_t* gtb = ws + GTB_OFF;
  const uint8_t* zblk = ws + ZERO_OFF;

#define ISSUE_B(T, BUFI) do {                                                 \
    const uint8_t* bsrc_ = ws + (size_t)((T) * 4 + octile) * BTAP_B;          \
    uint8_t* bdst_ = Bbuf + (BUFI) * BTAP_B;                                  \
    _Pragma("unroll")                                                         \
    for (int it = 0; it < 3; ++it) {                                          \
      int idx = it * 512 + tid;                                               \
      if (idx < 1152)                                                         \
        gload_lds16(bsrc_ + (size_t)idx * 16,                                 \
                    bdst_ + (size_t)(it * 512 + (tid & ~63)) * 16);           \
    }                                                                         \
  } while (0)

#define ISSUE_AROW(Y, SLOT) do {                                              \
    int y_ = (Y);                                                             \
    const uint8_t* src_ = (y_ >= 0 && y_ < 128)                               \
        ? (gtb + (size_t)(n * 128 + y_) * ROWBLK_B) : zblk;                   \
    uint8_t* dst_ = Abuf + (SLOT) * ROWBLK_B;                                 \
    _Pragma("unroll")                                                         \
    for (int it = 0; it < 3; ++it) {                                          \
      int idx = it * 512 + tid;                                               \
      if (idx < 1040)                                                         \
        gload_lds16(src_ + (size_t)idx * 16,                                  \
                    dst_ + (size_t)(it * 512 + (tid & ~63)) * 16);            \
    }                                                                         \
  } while (0)

  f32x4 acc[4][9];
  bf16x8 ar[2][4];                            // A frags, double-buffered by half
  bf16x8 br[4];                               // B ring, read-ahead 3 groups

// one kk-half: 9 groups of 4 MFMA. Consumes ar[AI] and window B frags
// IB..IB+8 (ring slot = frag&3); issues B frag IB+g+3 (if < WF, continuous
// across halves/taps of the window) and, if PFA, next half's A frags into
// ar[AI^1] one per group at g=5..8. All indices compile-time (full unroll).
#define HALF(IB, AI, WF, BUFA, BUFB, PFA, NDH, NDWP, NKK) do {                \
    _Pragma("unroll")                                                         \
    for (int g = 0; g < 9; ++g) {                                             \
      const int idx = (IB) + g;                                               \
      bf16x8 bcur_ = br[idx & 3];                                             \
      __builtin_amdgcn_s_setprio(1);                                          \
      _Pragma("unroll")                                                       \
      for (int mf = 0; mf < 4; ++mf)                                          \
        acc[mf][idx % 9] = __builtin_amdgcn_mfma_f32_16x16x32_bf16(           \
            bcur_, ar[AI][mf], acc[mf][idx % 9], 0, 0, 0);                    \
      __builtin_amdgcn_s_setprio(0);                                          \
      const int fi = idx + 3;                                                 \
      if (fi < (WF)) {                                                        \
        const int th = fi / 9;               /* window half 0..3 */           \
        const uint8_t* bb_ = Bbuf + (th >= 2 ? (BUFB) : (BUFA)) * BTAP_B;     \
        br[fi & 3] = *(const bf16x8*)(bb_ + bo[th & 1] + (fi % 9) * 2048);    \
      }                                                                       \
      if ((PFA) && g >= 5) {                                                  \
        const int mfp = g - 5;                                                \
        int idxs_ = mrow[mfp] + (NDH) + 1;       /* 0..5 */                   \
        int slot_ = (idxs_ == 5) ? 0 : idxs_;    /* row h0+4 in slot 0 */     \
        ar[(AI) ^ 1][mfp] = *(const bf16x8*)(Abuf + slot_ * ROWBLK_B          \
                                 + mcol[mfp] + aoff[NDWP][NKK]);              \
      }                                                                       \
    }                                                                         \
  } while (0)

// post-barrier storm: first half's A frags + B frags 0..2
#define WSTORM(DH0, DWP0, BUFA) do {                                          \
    _Pragma("unroll")                                                         \
    for (int mf = 0; mf < 4; ++mf) {                                          \
      int idxs_ = mrow[mf] + (DH0) + 1;                                       \
      int slot_ = (idxs_ == 5) ? 0 : idxs_;                                   \
      ar[0][mf] = *(const bf16x8*)(Abuf + slot_ * ROWBLK_B + mcol[mf]         \
                                   + aoff[DWP0][0]);                          \
    }                                                                         \
    _Pragma("unroll")                                                         \
    for (int f = 0; f < 3; ++f)                                               \
      br[f] = *(const bf16x8*)(Bbuf + (BUFA) * BTAP_B + bo[0] + f * 2048);    \
  } while (0)

// 2-tap window: taps (DH0,DWP0) from BUFA and (DH1,DWP1) from BUFB, 36 frags
#define WINDOW2(BUFA, BUFB, DH0, DWP0, DH1, DWP1) do {                        \
    WSTORM(DH0, DWP0, BUFA);                                                  \
    HALF(0,  0, 36, BUFA, BUFB, 1, DH0, DWP0, 1);                             \
    HALF(9,  1, 36, BUFA, BUFB, 1, DH1, DWP1, 0);                             \
    HALF(18, 0, 36, BUFA, BUFB, 1, DH1, DWP1, 1);                             \
    HALF(27, 1, 36, BUFA, BUFB, 0, 0, 0, 0);                                  \
  } while (0)

// single-tap window (tap 8)
#define WINDOW1(BUFA, DH0, DWP0) do {                                         \
    WSTORM(DH0, DWP0, BUFA);                                                  \
    HALF(0, 0, 18, BUFA, BUFA, 1, DH0, DWP0, 1);                              \
    HALF(9, 1, 18, BUFA, BUFA, 0, 0, 0, 0);                                   \
  } while (0)

  // ---- prologue: A slots 0..4 (rows h0-1 .. h0+3) + B taps 0,1
#pragma unroll
  for (int row = 0; row < 5; ++row) ISSUE_AROW(h0 - 1 + row, row);
  ISSUE_B(0, 0);
  ISSUE_B(1, 1);

  // bias init overlaps the staging loads: acc[mf][nf][q] = bc for
  // oc = octile*144 + (l4*4+q)*9 + nf  (channel l4*4+q, dyn-tap nf)
#pragma unroll
  for (int nf = 0; nf < 9; ++nf) {
#pragma unroll
    for (int q = 0; q < 4; ++q) {
      float bias = bc[octile * 144 + (l4 * 4 + q) * 9 + nf];
      acc[0][nf][q] = bias; acc[1][nf][q] = bias;
      acc[2][nf][q] = bias; acc[3][nf][q] = bias;
    }
  }
  __syncthreads();                            // drain: A(5) + B0,B1 visible

  // ---- window 0: taps 0,1; prefetch taps 2,3
  ISSUE_B(2, 2); ISSUE_B(3, 3);
  WINDOW2(0, 1, -1, 0, -1, 1);
  __syncthreads();
  // ---- window 1: taps 2,3; prefetch taps 4,5 (buf0,1 freed by barrier)
  ISSUE_B(4, 0); ISSUE_B(5, 1);
  WINDOW2(2, 3, -1, 2, 0, 0);
  __syncthreads();
  // ---- window 2: taps 4,5; prefetch 6,7 + A row h0+4 -> slot 0
  //      (slot 0's old row h0-1 last read at tap 2; freed by window-1 barrier)
  ISSUE_B(6, 2); ISSUE_B(7, 3);
  ISSUE_AROW(h0 + 4, 0);
  WINDOW2(0, 1, 0, 1, 0, 2);
  __syncthreads();
  // ---- window 3: taps 6,7; prefetch tap 8
  ISSUE_B(8, 0);
  WINDOW2(2, 3, 1, 0, 1, 1);
  __syncthreads();
  // ---- tap 8; no trailing barrier (epilogue touches no LDS)
  WINDOW1(0, 1, 2);

  // ---- epilogue: register-direct. acc[mf][k][q] = filt(pixel(mf,l15),
  // channel l4*4+q, tap k). Pure VALU + global; no LDS.
  const float* grb = gr + (size_t)(n * 64 + octile * 16 + l4 * 4) * 16384;
  float* outb = out + (size_t)(n * 64 + octile * 16 + l4 * 4) * 16384;
#pragma unroll
  for (int mf = 0; mf < 4; ++mf) {
    int p = (wv * 4 + mf) * 16 + l15;         // pixel within 512-pixel tile
    int hrow = p >> 7, w = p & 127;
    int h = h0 + hrow;
    int off[3][3];                            // replicate-clamped, shared over q
#pragma unroll
    for (int i = 0; i < 3; ++i) {
      int yy = h + i - 1; yy = yy < 0 ? 0 : (yy > 127 ? 127 : yy);
#pragma unroll
      for (int j = 0; j < 3; ++j) {
        int xx = w + j - 1; xx = xx < 0 ? 0 : (xx > 127 ? 127 : xx);
        off[i][j] = yy * 128 + xx;
      }
    }
#pragma unroll
    for (int q = 0; q < 4; ++q) {
      const float* grc = grb + (size_t)q * 16384;
      float s = 0.f;
#pragma unroll
      for (int i = 0; i < 3; ++i)
#pragma unroll
        for (int j = 0; j < 3; ++j)
          s = fmaf(acc[mf][i * 3 + j][q], grc[off[i][j]], s);
      outb[(size_t)q * 16384 + h * 128 + w] = s;
    }
  }
}

extern "C" void kernel_launch(void* const* d_in, const int* in_sizes, int n_in,
                              void* d_out, int out_size, void* d_ws, size_t ws_size,
                              hipStream_t stream) {
  const float* gr = (const float*)d_in[0];
  const float* gt = (const float*)d_in[1];
  const float* Wc = (const float*)d_in[2];
  const float* bc = (const float*)d_in[3];
  uint8_t* ws = (uint8_t*)d_ws;
  float* out = (float*)d_out;

  prep_wc<<<162, 256, 0, stream>>>(Wc, ws);
  prep_gt<<<1025, 256, 0, stream>>>(gt, ws);
  dfn_mfma<<<1024, 512, 0, stream>>>(gr, bc, ws, out);
}